// Round 2
// baseline (310.649 us; speedup 1.0000x reference)
//
#include <hip/hip_runtime.h>

// QRDQN n-step TD error, fused single kernel.
// B=16384, N=32, TAU=64, NSTEP=5, gamma=0.99.
// out[0] = loss, out[1..B] = td_err_per_sample.
//
// Layout: one wave per sample b. Lane i holds q_s_a[i] and tau_i.
// target[j] staged in LDS (1 KB/block), broadcast via uniform ds_read.
// Huber split: h(u) = h(max(u,0)) + h(min(u,0)) lets the tau weighting
// hoist out of the 64-iter inner loop:
//   sum_j |tau_i - 1{u<=0}| * h(u_ij) = tau_i*accP + (1-tau_i)*accN
// Inner body = 9 VALU f32 ops, no cmp/cndmask, no shfl/bpermute.

#define B_TOTAL 16384
#define N_ACT 32
#define TAU 64
#define NSTEP 5
#define GAMMA 0.99f
#define WPB 4                       // waves per block
#define NBLOCKS (B_TOTAL / WPB)     // 4096

__global__ __launch_bounds__(256) void qrdqn_fused_kernel(
    const float* __restrict__ q,
    const float* __restrict__ next_n_q,
    const int*   __restrict__ action,
    const int*   __restrict__ next_n_action,
    const float* __restrict__ reward,
    const float* __restrict__ done,
    const float* __restrict__ weight,
    float* __restrict__ out,          // [0]=loss, [1..B]=td
    float* __restrict__ ws_partial,   // NBLOCKS floats
    unsigned int* __restrict__ ticket) // 1 uint, zeroed via memsetAsync
{
    const int lane = threadIdx.x & 63;
    const int wave = threadIdx.x >> 6;
    const int b = blockIdx.x * WPB + wave;   // wave-uniform

    const int act  = action[b];
    const int nact = next_n_action[b];

    // n-step discounted reward (wave-uniform scalar work)
    float r = 0.0f, g = 1.0f;
    #pragma unroll
    for (int i = 0; i < NSTEP; ++i) {
        r += g * reward[i * B_TOTAL + b];
        g *= GAMMA;
    }
    const float vg = g * (1.0f - done[b]);   // gamma^nstep * (1-done)

    // coalesced row gathers: 64 lanes read 64 consecutive floats
    const float qi = q[((size_t)b * N_ACT + act) * TAU + lane];
    const float tq = next_n_q[((size_t)b * N_ACT + nact) * TAU + lane];
    const float tgt = fmaf(vg, tq, r);       // target quantile (lane = j)

    __shared__ float sm_t[WPB][TAU];
    __shared__ float sred[WPB];
    sm_t[wave][lane] = tgt;
    __syncthreads();

    // inner loop: lane = i (q quantile), j broadcast from LDS
    float accP = 0.0f, accN = 0.0f;
    #pragma unroll
    for (int j = 0; j < TAU; ++j) {
        const float tj = sm_t[wave][j];      // uniform-addr broadcast read
        const float u  = tj - qi;
        const float p  = fmaxf(u, 0.0f);
        const float n  = fminf(u, 0.0f);
        const float mp = fminf(p, 1.0f);
        const float mn = fminf(-n, 1.0f);
        accP = fmaf(mp, fmaf(-0.5f, mp, p),  accP);  // huber(u>0 part)
        accN = fmaf(mn, fmaf(-0.5f, mn, -n), accN);  // huber(u<=0 part)
    }
    const float tau_i = ((float)lane + 0.5f) * (1.0f / (float)TAU);
    // tau_i*accP + (1-tau_i)*accN
    float val = fmaf(tau_i, accP - accN, accN);

    // sum over lanes (= sum over i), then mean over i via 1/TAU
    #pragma unroll
    for (int off = 32; off > 0; off >>= 1)
        val += __shfl_xor(val, off, 64);
    const float td = val * (1.0f / (float)TAU);

    if (lane == 0) {
        out[1 + b]  = td;
        sred[wave]  = td * weight[b];
    }
    __syncthreads();

    // one partial per block, last block reduces all partials
    __shared__ unsigned s_tk;
    if (threadIdx.x == 0) {
        ws_partial[blockIdx.x] = sred[0] + sred[1] + sred[2] + sred[3];
        __threadfence();                       // release partial
        s_tk = atomicAdd(ticket, 1u);          // device-scope
    }
    __syncthreads();
    if (s_tk == NBLOCKS - 1) {                 // block-uniform branch
        __threadfence();                       // acquire partials
        float s = 0.0f;
        #pragma unroll
        for (int k = 0; k < NBLOCKS / 256; ++k)
            s += ws_partial[k * 256 + threadIdx.x];
        #pragma unroll
        for (int off = 32; off > 0; off >>= 1)
            s += __shfl_xor(s, off, 64);
        __shared__ float sr2[WPB];
        if (lane == 0) sr2[wave] = s;
        __syncthreads();
        if (threadIdx.x == 0)
            out[0] = (sr2[0] + sr2[1] + sr2[2] + sr2[3]) * (1.0f / (float)B_TOTAL);
    }
}

extern "C" void kernel_launch(void* const* d_in, const int* in_sizes, int n_in,
                              void* d_out, int out_size, void* d_ws, size_t ws_size,
                              hipStream_t stream)
{
    const float* q      = (const float*)d_in[0];
    const float* nq     = (const float*)d_in[1];
    const int*   act    = (const int*)d_in[2];
    const int*   nact   = (const int*)d_in[3];
    const float* reward = (const float*)d_in[4];
    const float* done   = (const float*)d_in[5];
    const float* weight = (const float*)d_in[6];
    float* out = (float*)d_out;

    float*        ws_partial = (float*)d_ws;                 // NBLOCKS floats
    unsigned int* ticket     = (unsigned int*)((char*)d_ws + NBLOCKS * sizeof(float));

    hipMemsetAsync(ticket, 0, sizeof(unsigned int), stream); // graph-capture legal
    qrdqn_fused_kernel<<<NBLOCKS, 256, 0, stream>>>(
        q, nq, act, nact, reward, done, weight, out, ws_partial, ticket);
}

// Round 3
// 235.327 us; speedup vs baseline: 1.3201x; 1.3201x over previous
//
#include <hip/hip_runtime.h>

// QRDQN n-step TD error. B=16384, N=32, TAU=64, NSTEP=5, gamma=0.99.
// out[0] = loss, out[1..B] = td_err_per_sample.
//
// R3: two-kernel structure (R2's fused atomic tail serialized the grid:
// 4096 same-line device atomics + threadfence ≈ +70 µs). Main kernel has
// NO barriers: each wave stages its own 64 targets in a wave-private LDS
// row (broadcast reads, conflict-free), per-wave partial to ws. Huber
// split h(u)=h(u+)+h(u-) hoists the tau weighting out of the inner loop.

#define B_TOTAL 16384
#define N_ACT 32
#define TAU 64
#define NSTEP 5
#define GAMMA 0.99f
#define WPB 4                       // waves per block
#define NBLOCKS (B_TOTAL / WPB)     // 4096

__global__ __launch_bounds__(256) void qrdqn_td_kernel(
    const float* __restrict__ q,
    const float* __restrict__ next_n_q,
    const int*   __restrict__ action,
    const int*   __restrict__ next_n_action,
    const float* __restrict__ reward,
    const float* __restrict__ done,
    const float* __restrict__ weight,
    float* __restrict__ out_td,      // d_out + 1 (B entries)
    float* __restrict__ ws_partial)  // B floats: td*weight per sample
{
    const int lane = threadIdx.x & 63;
    const int wave = threadIdx.x >> 6;
    const int b = blockIdx.x * WPB + wave;   // wave-uniform

    // independent preamble loads (issue together, one wait)
    const int   act  = action[b];
    const int   nact = next_n_action[b];
    const float dn   = done[b];
    const float wgt  = weight[b];

    float r = 0.0f, g = 1.0f;
    #pragma unroll
    for (int i = 0; i < NSTEP; ++i) {
        r += g * reward[i * B_TOTAL + b];
        g *= GAMMA;
    }
    const float vg = g * (1.0f - dn);        // gamma^nstep * (1-done)

    // coalesced row gathers: 64 lanes read 64 consecutive floats
    const float qi = q[((size_t)b * N_ACT + act) * TAU + lane];
    const float tq = next_n_q[((size_t)b * N_ACT + nact) * TAU + lane];
    const float tgt = fmaf(vg, tq, r);       // target quantile (lane = j)

    // wave-private LDS row; no __syncthreads needed (same-wave RAW,
    // compiler inserts lgkmcnt wait)
    __shared__ float sm_t[WPB][TAU];
    sm_t[wave][lane] = tgt;

    // inner loop: lane = i (q quantile), j broadcast from LDS as float4
    float accP = 0.0f, accN = 0.0f;
    const float4* trow = (const float4*)sm_t[wave];
    #pragma unroll
    for (int j4 = 0; j4 < TAU / 4; ++j4) {
        const float4 t4 = trow[j4];          // ds_read_b128, uniform addr
        #pragma unroll
        for (int e = 0; e < 4; ++e) {
            const float tj = (e == 0) ? t4.x : (e == 1) ? t4.y : (e == 2) ? t4.z : t4.w;
            const float u  = tj - qi;
            const float p  = fmaxf(u, 0.0f);
            const float n  = fminf(u, 0.0f);
            const float mp = fminf(p, 1.0f);
            const float mn = fminf(-n, 1.0f);
            accP = fmaf(mp, fmaf(-0.5f, mp, p),  accP);  // huber, u>0 part
            accN = fmaf(mn, fmaf(-0.5f, mn, -n), accN);  // huber, u<=0 part
        }
    }
    const float tau_i = ((float)lane + 0.5f) * (1.0f / (float)TAU);
    float val = fmaf(tau_i, accP - accN, accN);  // tau_i*accP + (1-tau_i)*accN

    // sum over lanes (= sum over i); mean over i via 1/TAU
    #pragma unroll
    for (int off = 32; off > 0; off >>= 1)
        val += __shfl_xor(val, off, 64);
    const float td = val * (1.0f / (float)TAU);

    if (lane == 0) {
        out_td[b]      = td;
        ws_partial[b]  = td * wgt;
    }
}

__global__ __launch_bounds__(256) void qrdqn_loss_kernel(
    const float4* __restrict__ part4, float* __restrict__ out_loss)
{
    float s = 0.0f;
    #pragma unroll
    for (int k = 0; k < B_TOTAL / 4 / 256; ++k) {   // 16 float4 each
        const float4 v = part4[k * 256 + threadIdx.x];
        s += (v.x + v.y) + (v.z + v.w);
    }
    #pragma unroll
    for (int off = 32; off > 0; off >>= 1)
        s += __shfl_xor(s, off, 64);
    __shared__ float sr[4];
    const int wave = threadIdx.x >> 6;
    if ((threadIdx.x & 63) == 0) sr[wave] = s;
    __syncthreads();
    if (threadIdx.x == 0)
        out_loss[0] = (sr[0] + sr[1] + sr[2] + sr[3]) * (1.0f / (float)B_TOTAL);
}

extern "C" void kernel_launch(void* const* d_in, const int* in_sizes, int n_in,
                              void* d_out, int out_size, void* d_ws, size_t ws_size,
                              hipStream_t stream)
{
    const float* q      = (const float*)d_in[0];
    const float* nq     = (const float*)d_in[1];
    const int*   act    = (const int*)d_in[2];
    const int*   nact   = (const int*)d_in[3];
    const float* reward = (const float*)d_in[4];
    const float* done   = (const float*)d_in[5];
    const float* weight = (const float*)d_in[6];
    float* out = (float*)d_out;

    float* ws_partial = (float*)d_ws;   // B_TOTAL floats

    qrdqn_td_kernel<<<NBLOCKS, 256, 0, stream>>>(
        q, nq, act, nact, reward, done, weight, out + 1, ws_partial);
    qrdqn_loss_kernel<<<1, 256, 0, stream>>>((const float4*)ws_partial, out);
}

// Round 4
// 234.867 us; speedup vs baseline: 1.3227x; 1.0020x over previous
//
#include <hip/hip_runtime.h>

// QRDQN n-step TD error. B=16384, N=32, TAU=64, NSTEP=5, gamma=0.99.
// out[0] = loss, out[1..B] = td_err_per_sample.
//
// R4: inner loop 9 -> 7 VALU/pair via v_med3_f32 clamps
// (__builtin_amdgcn_fmed3f). huber_plus = mp*(u - 0.5mp) with mp =
// med3(u,0,1) is exact even for u<=0 (mp=0 kills the product), so the
// separate p=max(u,0)/n=min(u,0) terms disappear. -u via free neg mods.
// Structure from R3: no barriers, wave-private LDS broadcast row,
// per-wave partials, tiny second kernel for the mean (no atomics --
// R2 showed 4096 same-line device atomics cost ~+70 us).

#define B_TOTAL 16384
#define N_ACT 32
#define TAU 64
#define NSTEP 5
#define GAMMA 0.99f
#define WPB 4                       // waves per block
#define NBLOCKS (B_TOTAL / WPB)     // 4096

__global__ __launch_bounds__(256) void qrdqn_td_kernel(
    const float* __restrict__ q,
    const float* __restrict__ next_n_q,
    const int*   __restrict__ action,
    const int*   __restrict__ next_n_action,
    const float* __restrict__ reward,
    const float* __restrict__ done,
    const float* __restrict__ weight,
    float* __restrict__ out_td,      // d_out + 1 (B entries)
    float* __restrict__ ws_partial)  // B floats: td*weight per sample
{
    const int lane = threadIdx.x & 63;
    const int wave = threadIdx.x >> 6;
    int b = blockIdx.x * WPB + wave;
    b = __builtin_amdgcn_readfirstlane(b);   // force s_load preamble

    const int   act  = action[b];
    const int   nact = next_n_action[b];
    const float dn   = done[b];
    const float wgt  = weight[b];

    float r = 0.0f, g = 1.0f;
    #pragma unroll
    for (int i = 0; i < NSTEP; ++i) {
        r += g * reward[i * B_TOTAL + b];
        g *= GAMMA;
    }
    const float vg = g * (1.0f - dn);        // gamma^nstep * (1-done)

    // coalesced row gathers: 64 lanes read 64 consecutive floats
    const float qi = q[((size_t)b * N_ACT + act) * TAU + lane];
    const float tq = next_n_q[((size_t)b * N_ACT + nact) * TAU + lane];
    const float tgt = fmaf(vg, tq, r);       // target quantile (lane = j)

    // wave-private LDS row; same-wave RAW -> compiler lgkmcnt, no barrier
    __shared__ float sm_t[WPB][TAU];
    sm_t[wave][lane] = tgt;

    const float nqi = -qi;                   // hoist: u = tj + nqi
    float aP0 = 0.0f, aP1 = 0.0f, aN0 = 0.0f, aN1 = 0.0f;
    const float4* trow = (const float4*)sm_t[wave];
    #pragma unroll
    for (int j4 = 0; j4 < TAU / 4; ++j4) {
        const float4 t4 = trow[j4];          // ds_read_b128, uniform addr
        const float u0 = t4.x + nqi;
        const float u1 = t4.y + nqi;
        const float u2 = t4.z + nqi;
        const float u3 = t4.w + nqi;
        // clamp(u,0,1) in one v_med3_f32
        const float mp0 = __builtin_amdgcn_fmed3f(u0, 0.0f, 1.0f);
        const float mp1 = __builtin_amdgcn_fmed3f(u1, 0.0f, 1.0f);
        const float mp2 = __builtin_amdgcn_fmed3f(u2, 0.0f, 1.0f);
        const float mp3 = __builtin_amdgcn_fmed3f(u3, 0.0f, 1.0f);
        const float mn0 = __builtin_amdgcn_fmed3f(-u0, 0.0f, 1.0f);
        const float mn1 = __builtin_amdgcn_fmed3f(-u1, 0.0f, 1.0f);
        const float mn2 = __builtin_amdgcn_fmed3f(-u2, 0.0f, 1.0f);
        const float mn3 = __builtin_amdgcn_fmed3f(-u3, 0.0f, 1.0f);
        // huber halves: m*(|u|_signed - 0.5m); u<=0 side uses -u (neg mod)
        aP0 = fmaf(mp0, fmaf(-0.5f, mp0, u0), aP0);
        aP1 = fmaf(mp1, fmaf(-0.5f, mp1, u1), aP1);
        aP0 = fmaf(mp2, fmaf(-0.5f, mp2, u2), aP0);
        aP1 = fmaf(mp3, fmaf(-0.5f, mp3, u3), aP1);
        aN0 = fmaf(mn0, fmaf(-0.5f, mn0, -u0), aN0);
        aN1 = fmaf(mn1, fmaf(-0.5f, mn1, -u1), aN1);
        aN0 = fmaf(mn2, fmaf(-0.5f, mn2, -u2), aN0);
        aN1 = fmaf(mn3, fmaf(-0.5f, mn3, -u3), aN1);
    }
    const float accP = aP0 + aP1;
    const float accN = aN0 + aN1;
    const float tau_i = ((float)lane + 0.5f) * (1.0f / (float)TAU);
    float val = fmaf(tau_i, accP - accN, accN);  // tau_i*accP + (1-tau_i)*accN

    // sum over lanes (= sum over i); mean over i via 1/TAU
    #pragma unroll
    for (int off = 32; off > 0; off >>= 1)
        val += __shfl_xor(val, off, 64);
    const float td = val * (1.0f / (float)TAU);

    if (lane == 0) {
        out_td[b]     = td;
        ws_partial[b] = td * wgt;
    }
}

__global__ __launch_bounds__(256) void qrdqn_loss_kernel(
    const float4* __restrict__ part4, float* __restrict__ out_loss)
{
    float s = 0.0f;
    #pragma unroll
    for (int k = 0; k < B_TOTAL / 4 / 256; ++k) {   // 16 float4 each
        const float4 v = part4[k * 256 + threadIdx.x];
        s += (v.x + v.y) + (v.z + v.w);
    }
    #pragma unroll
    for (int off = 32; off > 0; off >>= 1)
        s += __shfl_xor(s, off, 64);
    __shared__ float sr[4];
    const int wave = threadIdx.x >> 6;
    if ((threadIdx.x & 63) == 0) sr[wave] = s;
    __syncthreads();
    if (threadIdx.x == 0)
        out_loss[0] = (sr[0] + sr[1] + sr[2] + sr[3]) * (1.0f / (float)B_TOTAL);
}

extern "C" void kernel_launch(void* const* d_in, const int* in_sizes, int n_in,
                              void* d_out, int out_size, void* d_ws, size_t ws_size,
                              hipStream_t stream)
{
    const float* q      = (const float*)d_in[0];
    const float* nq     = (const float*)d_in[1];
    const int*   act    = (const int*)d_in[2];
    const int*   nact   = (const int*)d_in[3];
    const float* reward = (const float*)d_in[4];
    const float* done   = (const float*)d_in[5];
    const float* weight = (const float*)d_in[6];
    float* out = (float*)d_out;

    float* ws_partial = (float*)d_ws;   // B_TOTAL floats

    qrdqn_td_kernel<<<NBLOCKS, 256, 0, stream>>>(
        q, nq, act, nact, reward, done, weight, out + 1, ws_partial);
    qrdqn_loss_kernel<<<1, 256, 0, stream>>>((const float4*)ws_partial, out);
}

// Round 5
// 234.387 us; speedup vs baseline: 1.3254x; 1.0021x over previous
//
#include <hip/hip_runtime.h>

// QRDQN n-step TD error. B=16384, N=32, TAU=64, NSTEP=5, gamma=0.99.
// out[0] = loss, out[1..B] = td_err_per_sample.
//
// R5: (a) inner loop on float2 ext-vectors + __builtin_elementwise_fma so
// the backend can select VOP3P v_pk_add_f32 / v_pk_fma_f32 (9 inst per 2
// pairs vs 14 scalar); med3 clamps stay scalar (no packed med3).
// (b) td kernel emits one partial per BLOCK (LDS + one __syncthreads --
// intra-block, not R2's fatal global atomic), so the loss kernel reads
// 16 KB instead of 64 KB.
// Structure: no global sync, wave-private LDS broadcast row, two kernels.

#define B_TOTAL 16384
#define N_ACT 32
#define TAU 64
#define NSTEP 5
#define GAMMA 0.99f
#define WPB 4                       // waves per block
#define NBLOCKS (B_TOTAL / WPB)     // 4096

typedef float v2f __attribute__((ext_vector_type(2)));

__global__ __launch_bounds__(256) void qrdqn_td_kernel(
    const float* __restrict__ q,
    const float* __restrict__ next_n_q,
    const int*   __restrict__ action,
    const int*   __restrict__ next_n_action,
    const float* __restrict__ reward,
    const float* __restrict__ done,
    const float* __restrict__ weight,
    float* __restrict__ out_td,      // d_out + 1 (B entries)
    float* __restrict__ ws_partial)  // NBLOCKS floats: per-block sum td*w
{
    const int lane = threadIdx.x & 63;
    const int wave = threadIdx.x >> 6;
    int b = blockIdx.x * WPB + wave;
    b = __builtin_amdgcn_readfirstlane(b);   // force s_load preamble

    const int   act  = action[b];
    const int   nact = next_n_action[b];
    const float dn   = done[b];
    const float wgt  = weight[b];

    float r = 0.0f, g = 1.0f;
    #pragma unroll
    for (int i = 0; i < NSTEP; ++i) {
        r += g * reward[i * B_TOTAL + b];
        g *= GAMMA;
    }
    const float vg = g * (1.0f - dn);        // gamma^nstep * (1-done)

    // coalesced row gathers: 64 lanes read 64 consecutive floats
    const float qi = q[((size_t)b * N_ACT + act) * TAU + lane];
    const float tq = next_n_q[((size_t)b * N_ACT + nact) * TAU + lane];
    const float tgt = fmaf(vg, tq, r);       // target quantile (lane = j)

    // wave-private LDS row; same-wave RAW -> compiler lgkmcnt, no barrier
    __shared__ float sm_t[WPB][TAU];
    sm_t[wave][lane] = tgt;

    const v2f nqi2  = (v2f)(-qi);
    const v2f half2 = (v2f)(-0.5f);
    v2f aP0 = (v2f)(0.0f), aP1 = (v2f)(0.0f);
    v2f aN0 = (v2f)(0.0f), aN1 = (v2f)(0.0f);
    const float4* trow = (const float4*)sm_t[wave];
    #pragma unroll
    for (int j4 = 0; j4 < TAU / 4; ++j4) {
        const float4 t4 = trow[j4];          // ds_read_b128, uniform addr
        const v2f u01 = (v2f){t4.x, t4.y} + nqi2;   // v_pk_add_f32
        const v2f u23 = (v2f){t4.z, t4.w} + nqi2;
        // clamp(u,0,1) / clamp(-u,0,1): scalar v_med3_f32
        const v2f mp01 = (v2f){__builtin_amdgcn_fmed3f(u01.x, 0.0f, 1.0f),
                               __builtin_amdgcn_fmed3f(u01.y, 0.0f, 1.0f)};
        const v2f mp23 = (v2f){__builtin_amdgcn_fmed3f(u23.x, 0.0f, 1.0f),
                               __builtin_amdgcn_fmed3f(u23.y, 0.0f, 1.0f)};
        const v2f mn01 = (v2f){__builtin_amdgcn_fmed3f(-u01.x, 0.0f, 1.0f),
                               __builtin_amdgcn_fmed3f(-u01.y, 0.0f, 1.0f)};
        const v2f mn23 = (v2f){__builtin_amdgcn_fmed3f(-u23.x, 0.0f, 1.0f),
                               __builtin_amdgcn_fmed3f(-u23.y, 0.0f, 1.0f)};
        // huber halves: m*(u_signed - 0.5m), pk_fma pairs
        aP0 = __builtin_elementwise_fma(mp01, __builtin_elementwise_fma(half2, mp01, u01), aP0);
        aP1 = __builtin_elementwise_fma(mp23, __builtin_elementwise_fma(half2, mp23, u23), aP1);
        aN0 = __builtin_elementwise_fma(mn01, __builtin_elementwise_fma(half2, mn01, -u01), aN0);
        aN1 = __builtin_elementwise_fma(mn23, __builtin_elementwise_fma(half2, mn23, -u23), aN1);
    }
    const v2f aP = aP0 + aP1, aN = aN0 + aN1;
    const float accP = aP.x + aP.y;
    const float accN = aN.x + aN.y;
    const float tau_i = ((float)lane + 0.5f) * (1.0f / (float)TAU);
    float val = fmaf(tau_i, accP - accN, accN);  // tau_i*accP + (1-tau_i)*accN

    // sum over lanes (= sum over i); mean over i via 1/TAU
    #pragma unroll
    for (int off = 32; off > 0; off >>= 1)
        val += __shfl_xor(val, off, 64);
    const float td = val * (1.0f / (float)TAU);

    __shared__ float sred[WPB];
    if (lane == 0) {
        out_td[b]  = td;
        sred[wave] = td * wgt;
    }
    __syncthreads();                 // intra-block only (cheap)
    if (threadIdx.x == 0)
        ws_partial[blockIdx.x] = (sred[0] + sred[1]) + (sred[2] + sred[3]);
}

__global__ __launch_bounds__(256) void qrdqn_loss_kernel(
    const float4* __restrict__ part4, float* __restrict__ out_loss)
{
    float s = 0.0f;
    #pragma unroll
    for (int k = 0; k < NBLOCKS / 4 / 256; ++k) {   // 4 float4 each
        const float4 v = part4[k * 256 + threadIdx.x];
        s += (v.x + v.y) + (v.z + v.w);
    }
    #pragma unroll
    for (int off = 32; off > 0; off >>= 1)
        s += __shfl_xor(s, off, 64);
    __shared__ float sr[4];
    const int wave = threadIdx.x >> 6;
    if ((threadIdx.x & 63) == 0) sr[wave] = s;
    __syncthreads();
    if (threadIdx.x == 0)
        out_loss[0] = (sr[0] + sr[1] + sr[2] + sr[3]) * (1.0f / (float)B_TOTAL);
}

extern "C" void kernel_launch(void* const* d_in, const int* in_sizes, int n_in,
                              void* d_out, int out_size, void* d_ws, size_t ws_size,
                              hipStream_t stream)
{
    const float* q      = (const float*)d_in[0];
    const float* nq     = (const float*)d_in[1];
    const int*   act    = (const int*)d_in[2];
    const int*   nact   = (const int*)d_in[3];
    const float* reward = (const float*)d_in[4];
    const float* done   = (const float*)d_in[5];
    const float* weight = (const float*)d_in[6];
    float* out = (float*)d_out;

    float* ws_partial = (float*)d_ws;   // NBLOCKS floats

    qrdqn_td_kernel<<<NBLOCKS, 256, 0, stream>>>(
        q, nq, act, nact, reward, done, weight, out + 1, ws_partial);
    qrdqn_loss_kernel<<<1, 256, 0, stream>>>((const float4*)ws_partial, out);
}